// Round 15
// baseline (327.281 us; speedup 1.0000x reference)
//
#include <hip/hip_runtime.h>
#include <hip/hip_bf16.h>

#define NEG_SLOPE 0.2f

typedef short bf16x8 __attribute__((ext_vector_type(8)));
typedef float f32x4 __attribute__((ext_vector_type(4)));
typedef float f32x2 __attribute__((ext_vector_type(2)));

__device__ __forceinline__ unsigned short f2bf(float f) {
    unsigned int x = __float_as_uint(f);
    unsigned int lsb = (x >> 16) & 1u;
    x += 0x7fffu + lsb;
    return (unsigned short)(x >> 16);
}
__device__ __forceinline__ f32x2 upk(unsigned int u) {
    f32x2 r;
    r.x = __uint_as_float(u << 16);
    r.y = __uint_as_float(u & 0xffff0000u);
    return r;
}
__device__ __forceinline__ unsigned short f2h(float f) {
    _Float16 h = (_Float16)f;
    return *(unsigned short*)&h;
}
__device__ __forceinline__ float h2f(unsigned short u) {
    _Float16 h = *(_Float16*)&u;
    return (float)h;
}

// per-lane exclusive prefix of bsum[0..nb); consumers pick with __shfl.
// ALL 64 lanes of the wave must be active.
__device__ __forceinline__ int bsum_scan(const int* __restrict__ bsum, int nb) {
    int lane = threadIdx.x & 63;
    int v = (lane < nb) ? bsum[lane] : 0;
    int x = v;
    #pragma unroll
    for (int off = 1; off < 64; off <<= 1) {
        int t = __shfl_up(x, off);
        if (lane >= off) x += t;
    }
    return x - v;
}

// ---------------- prep: cast both weights + zero deg (one launch) ----------
__global__ void prep_kernel(const float* __restrict__ W1, const float* __restrict__ W2,
                            unsigned short* __restrict__ wt1, unsigned short* __restrict__ wt2,
                            int* __restrict__ deg, int N) {
    int idx = blockIdx.x * 256 + threadIdx.x;
    if (idx < 128 * 256) {
        int k = idx >> 8, n = idx & 255;
        wt1[(size_t)n * 128 + k] = f2bf(W1[idx]);
    } else if (idx < 2 * 128 * 256) {
        int j = idx - 128 * 256;
        int k = j >> 7, n = j & 127;
        wt2[(size_t)n * 256 + k] = f2bf(W2[j]);
    } else {
        int i = idx - 2 * 128 * 256;
        if (i < N) deg[i] = 0;
    }
}

// ---------------- CSR build ----------------
__global__ void degree_kernel(const int* __restrict__ ei, int E, int N,
                              int* __restrict__ deg, int* __restrict__ idx) {
    int e = blockIdx.x * blockDim.x + threadIdx.x;
    int EA = E + N;
    if (e >= EA) return;
    int dst = (e < E) ? ei[E + e] : (e - E);
    idx[e] = atomicAdd(&deg[dst], 1);
}

// per-block (1024) local exclusive scan; offs = LOCAL prefixes, bsum = totals.
__global__ void scan_local(const int* __restrict__ deg, int* __restrict__ offs,
                           int* __restrict__ bsum, int N) {
    __shared__ int wsum[16];
    int tid = threadIdx.x;
    int lane = tid & 63;
    int wave = tid >> 6;
    int i = blockIdx.x * 1024 + tid;
    int v = (i < N) ? deg[i] : 0;
    int x = v;
    #pragma unroll
    for (int off = 1; off < 64; off <<= 1) {
        int t = __shfl_up(x, off);
        if (lane >= off) x += t;
    }
    if (lane == 63) wsum[wave] = x;
    __syncthreads();
    if (wave == 0 && lane < 16) {
        int w = wsum[lane];
        #pragma unroll
        for (int off = 1; off < 16; off <<= 1) {
            int t = __shfl_up(w, off);
            if (lane >= off) w += t;
        }
        wsum[lane] = w;
    }
    __syncthreads();
    int wexcl = (wave > 0) ? wsum[wave - 1] : 0;
    if (i <= N) offs[i] = wexcl + x - v;
    if (tid == 0) bsum[blockIdx.x] = wsum[15];
}

// scatter (no atomics) + fused layer-1 edge-weight precompute (fp16 x4)
__global__ void scatter_kernel(const int* __restrict__ ei, int E, int N,
                               const int* __restrict__ offs, const int* __restrict__ idx,
                               const int* __restrict__ bsum, int nb,
                               const float* __restrict__ as1, const float* __restrict__ ad1,
                               int* __restrict__ colb, uint2* __restrict__ p1) {
    int e = blockIdx.x * blockDim.x + threadIdx.x;
    int EA = E + N;
    bool act = e < EA;
    int s = 0, d = 0;
    if (act) {
        if (e < E) { s = ei[e]; d = ei[E + e]; }
        else       { s = d = e - E; }
    }
    int pref = bsum_scan(bsum, nb);
    int excl = __shfl(pref, d >> 10);
    if (!act) return;
    int pos = offs[d] + excl + idx[e];
    colb[pos] = s << 9;
    float4 av = *(const float4*)(as1 + s * 4);
    float4 dv = *(const float4*)(ad1 + d * 4);
    float e0 = av.x + dv.x, e1 = av.y + dv.y, e2 = av.z + dv.z, e3 = av.w + dv.w;
    e0 = (e0 > 0.f) ? e0 : NEG_SLOPE * e0;
    e1 = (e1 > 0.f) ? e1 : NEG_SLOPE * e1;
    e2 = (e2 > 0.f) ? e2 : NEG_SLOPE * e2;
    e3 = (e3 > 0.f) ? e3 : NEG_SLOPE * e3;
    uint2 q;
    q.x = (unsigned int)f2h(__expf(e0)) | ((unsigned int)f2h(__expf(e1)) << 16);
    q.y = (unsigned int)f2h(__expf(e2)) | ((unsigned int)f2h(__expf(e3)) << 16);
    p1[pos] = q;
}

// ---------------- MFMA GEMM1 + fused x-cast + fused alpha1 ----------------
__global__ void gemm1_mfma(const float* __restrict__ A,
                           const unsigned short* __restrict__ Wt,
                           const float* __restrict__ att_s, const float* __restrict__ att_d,
                           unsigned short* __restrict__ hb,
                           float* __restrict__ as, float* __restrict__ ad, int M) {
    int wave = threadIdx.x >> 6;
    int lane = threadIdx.x & 63;
    int quad = lane >> 4;
    int l16 = lane & 15;
    int m0 = blockIdx.x * 64 + wave * 16;
    int rowc = min(m0 + l16, M - 1);
    bf16x8 a[4];
    const float* ap = A + (size_t)rowc * 128 + quad * 8;
    #pragma unroll
    for (int kc = 0; kc < 4; ++kc) {
        float4 f0 = *(const float4*)(ap + kc * 32);
        float4 f1 = *(const float4*)(ap + kc * 32 + 4);
        bf16x8 v;
        v[0] = (short)f2bf(f0.x); v[1] = (short)f2bf(f0.y);
        v[2] = (short)f2bf(f0.z); v[3] = (short)f2bf(f0.w);
        v[4] = (short)f2bf(f1.x); v[5] = (short)f2bf(f1.y);
        v[6] = (short)f2bf(f1.z); v[7] = (short)f2bf(f1.w);
        a[kc] = v;
    }
    f32x4 acc[16];
    #pragma unroll
    for (int nt = 0; nt < 16; ++nt) {
        f32x4 c = {0.f, 0.f, 0.f, 0.f};
        const unsigned short* bp = Wt + (size_t)(nt * 16 + l16) * 128 + quad * 8;
        #pragma unroll
        for (int kc = 0; kc < 4; ++kc) {
            bf16x8 b = *(const bf16x8*)(bp + kc * 32);
            c = __builtin_amdgcn_mfma_f32_16x16x32_bf16(a[kc], b, c, 0, 0, 0);
        }
        acc[nt] = c;
    }
    float asv[16], adv[16];
    #pragma unroll
    for (int nt = 0; nt < 16; ++nt) {
        asv[nt] = att_s[nt * 16 + l16];
        adv[nt] = att_d[nt * 16 + l16];
    }
    int srow0 = m0 + quad * 4;
    #pragma unroll
    for (int r = 0; r < 4; ++r) {
        int srow = srow0 + r;
        bool ok = srow < M;
        if (ok) {
            #pragma unroll
            for (int nt = 0; nt < 16; ++nt)
                hb[(size_t)srow * 256 + nt * 16 + l16] = f2bf(acc[nt][r]);
        }
        #pragma unroll
        for (int h = 0; h < 4; ++h) {
            float ps = acc[4 * h][r] * asv[4 * h] + acc[4 * h + 1][r] * asv[4 * h + 1]
                     + acc[4 * h + 2][r] * asv[4 * h + 2] + acc[4 * h + 3][r] * asv[4 * h + 3];
            float pd = acc[4 * h][r] * adv[4 * h] + acc[4 * h + 1][r] * adv[4 * h + 1]
                     + acc[4 * h + 2][r] * adv[4 * h + 2] + acc[4 * h + 3][r] * adv[4 * h + 3];
            #pragma unroll
            for (int off = 1; off < 16; off <<= 1) {
                ps += __shfl_xor(ps, off);
                pd += __shfl_xor(pd, off);
            }
            if (ok && l16 == 0) {
                as[srow * 4 + h] = ps;
                ad[srow * 4 + h] = pd;
            }
        }
    }
}

// ---------------- FUSED: layer-1 aggregation + GEMM2 + alpha2 ----------------
// 128 threads: 2 waves x 8 nodes (better makespan balance than 4x4), one
// barrier, XOR-swizzled unpadded [16][256] tile (0 conflicts, measured R13/R14).
// p1 read as per-head ushort (drops uint2 load + selects).
__global__ void agg1_gemm2(const unsigned short* __restrict__ hb,
                           const int* __restrict__ colb, const uint2* __restrict__ p1,
                           const int* __restrict__ offs,
                           const int* __restrict__ bsum, int nb,
                           const float* __restrict__ b1,
                           const unsigned short* __restrict__ Wt,
                           const float* __restrict__ att_s, const float* __restrict__ att_d,
                           unsigned short* __restrict__ h2b,
                           float* __restrict__ as2, float* __restrict__ ad2, int N) {
    __shared__ unsigned short Atile[16][256];   // 8 KB, XOR-swizzled
    __shared__ float asP[16], adP[16];
    int tid = threadIdx.x;
    int wave = tid >> 6;                         // 0..1
    int lane = tid & 63;
    if (tid < 16) { asP[tid] = 0.f; adP[tid] = 0.f; }
    int half = lane >> 5;
    int sub  = lane & 31;
    int head = sub >> 3;
    int c0b = sub * 16;
    const char* hpc = (const char*)hb;
    const unsigned short* p1u = (const unsigned short*)p1;
    int node0 = blockIdx.x * 16;
    int pref = bsum_scan(bsum, nb);

    // ---- phase 1: each wave aggregates 8 nodes into swizzled tile rows ----
    for (int t = 0; t < 8; ++t) {
        int lrow = wave * 8 + t;
        int node = min(node0 + lrow, N - 1);
        int beg = offs[node] + __shfl(pref, node >> 10);
        int end = offs[node + 1] + __shfl(pref, (node + 1) >> 10);
        float d = 0.f;
        f32x2 acc[4] = {};
        int j = beg + half;
        for (; j + 6 < end; j += 8) {
            int o0 = colb[j] + c0b;
            int o1 = colb[j + 2] + c0b;
            int o2 = colb[j + 4] + c0b;
            int o3 = colb[j + 6] + c0b;
            float p0 = h2f(p1u[(size_t)j * 4 + head]);
            float p1v = h2f(p1u[(size_t)(j + 2) * 4 + head]);
            float p2 = h2f(p1u[(size_t)(j + 4) * 4 + head]);
            float p3 = h2f(p1u[(size_t)(j + 6) * 4 + head]);
            uint4 g0 = *(const uint4*)(hpc + o0);
            uint4 g1 = *(const uint4*)(hpc + o1);
            uint4 g2 = *(const uint4*)(hpc + o2);
            uint4 g3 = *(const uint4*)(hpc + o3);
            d += (p0 + p1v) + (p2 + p3);
            const unsigned int* w0 = (const unsigned int*)&g0;
            const unsigned int* w1 = (const unsigned int*)&g1;
            const unsigned int* w2 = (const unsigned int*)&g2;
            const unsigned int* w3 = (const unsigned int*)&g3;
            f32x2 v0 = {p0, p0}, v1 = {p1v, p1v}, v2 = {p2, p2}, v3 = {p3, p3};
            #pragma unroll
            for (int i = 0; i < 4; ++i) {
                acc[i] = __builtin_elementwise_fma(v0, upk(w0[i]), acc[i]);
                acc[i] = __builtin_elementwise_fma(v1, upk(w1[i]), acc[i]);
                acc[i] = __builtin_elementwise_fma(v2, upk(w2[i]), acc[i]);
                acc[i] = __builtin_elementwise_fma(v3, upk(w3[i]), acc[i]);
            }
        }
        for (; j < end; j += 2) {
            int o = colb[j] + c0b;
            float p = h2f(p1u[(size_t)j * 4 + head]);
            uint4 g = *(const uint4*)(hpc + o);
            d += p;
            const unsigned int* w = (const unsigned int*)&g;
            f32x2 v = {p, p};
            #pragma unroll
            for (int i = 0; i < 4; ++i)
                acc[i] = __builtin_elementwise_fma(v, upk(w[i]), acc[i]);
        }
        d += __shfl_xor(d, 32);
        #pragma unroll
        for (int i = 0; i < 4; ++i) {
            acc[i].x += __shfl_xor(acc[i].x, 32);
            acc[i].y += __shfl_xor(acc[i].y, 32);
        }
        if (half == 0) {
            float inv = 1.f / d;
            int c0 = sub * 8;
            float4 bb0 = *(const float4*)(b1 + c0);
            float4 bb1 = *(const float4*)(b1 + c0 + 4);
            float av[8] = {acc[0].x, acc[0].y, acc[1].x, acc[1].y,
                           acc[2].x, acc[2].y, acc[3].x, acc[3].y};
            float bb[8] = {bb0.x, bb0.y, bb0.z, bb0.w, bb1.x, bb1.y, bb1.z, bb1.w};
            unsigned short o[8];
            #pragma unroll
            for (int i = 0; i < 8; ++i) {
                float v = av[i] * inv + bb[i];
                v = (v > 0.f) ? v : (__expf(v) - 1.f);
                o[i] = f2bf(v);
            }
            uint4 pk;
            pk.x = (unsigned int)o[0] | ((unsigned int)o[1] << 16);
            pk.y = (unsigned int)o[2] | ((unsigned int)o[3] << 16);
            pk.z = (unsigned int)o[4] | ((unsigned int)o[5] << 16);
            pk.w = (unsigned int)o[6] | ((unsigned int)o[7] << 16);
            *(uint4*)&Atile[lrow][(sub ^ lrow) * 8] = pk;   // swizzled group
        }
    }
    __syncthreads();

    // ---- phase 2: 16x128 = Atile(16x256) @ wt2; wave owns n-tiles 4w..4w+3 ----
    int quad = lane >> 4;
    int l16 = lane & 15;
    bf16x8 a[8];
    #pragma unroll
    for (int kc = 0; kc < 8; ++kc) {
        int grp = (kc * 4 + quad) ^ l16;             // unswizzle for row l16
        a[kc] = *(const bf16x8*)&Atile[l16][grp * 8];
    }
    int nt0 = wave * 4;
    f32x4 acc2[4];
    #pragma unroll
    for (int i = 0; i < 4; ++i) {
        f32x4 c = {0.f, 0.f, 0.f, 0.f};
        const unsigned short* bp = Wt + (size_t)((nt0 + i) * 16 + l16) * 256 + quad * 8;
        #pragma unroll
        for (int kc = 0; kc < 8; ++kc) {
            bf16x8 b = *(const bf16x8*)(bp + kc * 32);
            c = __builtin_amdgcn_mfma_f32_16x16x32_bf16(a[kc], b, c, 0, 0, 0);
        }
        acc2[i] = c;
    }
    float sv[4], dv[4];
    #pragma unroll
    for (int i = 0; i < 4; ++i) {
        sv[i] = att_s[(nt0 + i) * 16 + l16];
        dv[i] = att_d[(nt0 + i) * 16 + l16];
    }
    #pragma unroll
    for (int r = 0; r < 4; ++r) {
        int row = quad * 4 + r;
        int grow = node0 + row;
        if (grow < N) {
            #pragma unroll
            for (int i = 0; i < 4; ++i)
                h2b[(size_t)grow * 128 + (nt0 + i) * 16 + l16] = f2bf(acc2[i][r]);
        }
        float ps = 0.f, pd = 0.f;
        #pragma unroll
        for (int i = 0; i < 4; ++i) {
            ps = fmaf(acc2[i][r], sv[i], ps);
            pd = fmaf(acc2[i][r], dv[i], pd);
        }
        #pragma unroll
        for (int off = 1; off < 16; off <<= 1) {
            ps += __shfl_xor(ps, off);
            pd += __shfl_xor(pd, off);
        }
        if (l16 == 0) {
            atomicAdd(&asP[row], ps);
            atomicAdd(&adP[row], pd);
        }
    }
    __syncthreads();
    if (tid < 16 && node0 + tid < N) {
        as2[node0 + tid] = asP[tid];
        ad2[node0 + tid] = adP[tid];
    }
}

// ---------------- layer-2 aggregation (hoisted bsum scan) ----------------
__global__ void agg2_kernel(const unsigned short* __restrict__ hb,
                            const float* __restrict__ as,
                            const float* __restrict__ ad,
                            const int* __restrict__ offs, const int* __restrict__ colb,
                            const int* __restrict__ bsum, int nb,
                            const float* __restrict__ b2,
                            float* __restrict__ out, int N) {
    int node = blockIdx.x * 4 + (threadIdx.x >> 6);
    if (node >= N) return;
    int lane = threadIdx.x & 63;
    int q   = lane >> 4;
    int sub = lane & 15;
    int c0b = sub * 16;
    const char* hpc = (const char*)hb;
    float adv = ad[node];
    int pref = bsum_scan(bsum, nb);
    int beg = offs[node] + __shfl(pref, node >> 10);
    int end = offs[node + 1] + __shfl(pref, (node + 1) >> 10);
    float d = 0.f;
    f32x2 acc[4] = {};
    int j = beg + q;
    for (; j + 4 < end; j += 8) {
        int cb0 = colb[j];
        int cb1 = colb[j + 4];
        uint4 g0 = *(const uint4*)(hpc + (cb0 >> 1) + c0b);
        uint4 g1 = *(const uint4*)(hpc + (cb1 >> 1) + c0b);
        float e0 = as[cb0 >> 9] + adv;
        float e1 = as[cb1 >> 9] + adv;
        e0 = (e0 > 0.f) ? e0 : NEG_SLOPE * e0;
        e1 = (e1 > 0.f) ? e1 : NEG_SLOPE * e1;
        float p0 = __expf(e0), p1 = __expf(e1);
        d += p0 + p1;
        const unsigned int* w0 = (const unsigned int*)&g0;
        const unsigned int* w1 = (const unsigned int*)&g1;
        f32x2 v0 = {p0, p0}, v1 = {p1, p1};
        #pragma unroll
        for (int i = 0; i < 4; ++i) {
            acc[i] = __builtin_elementwise_fma(v0, upk(w0[i]), acc[i]);
            acc[i] = __builtin_elementwise_fma(v1, upk(w1[i]), acc[i]);
        }
    }
    for (; j < end; j += 4) {
        int cb = colb[j];
        uint4 g = *(const uint4*)(hpc + (cb >> 1) + c0b);
        float e = as[cb >> 9] + adv;
        e = (e > 0.f) ? e : NEG_SLOPE * e;
        float p = __expf(e);
        d += p;
        const unsigned int* w = (const unsigned int*)&g;
        f32x2 v = {p, p};
        #pragma unroll
        for (int i = 0; i < 4; ++i)
            acc[i] = __builtin_elementwise_fma(v, upk(w[i]), acc[i]);
    }
    d += __shfl_xor(d, 16);
    d += __shfl_xor(d, 32);
    #pragma unroll
    for (int i = 0; i < 4; ++i) {
        acc[i].x += __shfl_xor(acc[i].x, 16);
        acc[i].x += __shfl_xor(acc[i].x, 32);
        acc[i].y += __shfl_xor(acc[i].y, 16);
        acc[i].y += __shfl_xor(acc[i].y, 32);
    }
    if (lane < 16) {
        float inv = 1.f / d;
        int c0 = sub * 8;
        float4 bb0 = *(const float4*)(b2 + c0);
        float4 bb1 = *(const float4*)(b2 + c0 + 4);
        float av[8] = {acc[0].x, acc[0].y, acc[1].x, acc[1].y,
                       acc[2].x, acc[2].y, acc[3].x, acc[3].y};
        float bb[8] = {bb0.x, bb0.y, bb0.z, bb0.w, bb1.x, bb1.y, bb1.z, bb1.w};
        *(float4*)(out + (size_t)node * 128 + c0) =
            make_float4(av[0] * inv + bb[0], av[1] * inv + bb[1],
                        av[2] * inv + bb[2], av[3] * inv + bb[3]);
        *(float4*)(out + (size_t)node * 128 + c0 + 4) =
            make_float4(av[4] * inv + bb[4], av[5] * inv + bb[5],
                        av[6] * inv + bb[6], av[7] * inv + bb[7]);
    }
}

// ---------------- launch (7 dispatches) ----------------

extern "C" void kernel_launch(void* const* d_in, const int* in_sizes, int n_in,
                              void* d_out, int out_size, void* d_ws, size_t ws_size,
                              hipStream_t stream) {
    const float* x    = (const float*)d_in[0];
    const int*   ei   = (const int*)d_in[1];
    const float* W1   = (const float*)d_in[2];
    const float* at_s1 = (const float*)d_in[3];
    const float* at_d1 = (const float*)d_in[4];
    const float* b1   = (const float*)d_in[5];
    const float* W2   = (const float*)d_in[6];
    const float* at_s2 = (const float*)d_in[7];
    const float* at_d2 = (const float*)d_in[8];
    const float* b2   = (const float*)d_in[9];
    float* out = (float*)d_out;

    const int N  = in_sizes[0] / 128;
    const int E  = in_sizes[1] / 2;
    const int EA = E + N;

    char* ws = (char*)d_ws;
    size_t off = 0;
    auto alloc = [&](size_t bytes) -> void* {
        void* p = ws + off;
        off += (bytes + 255) & ~(size_t)255;
        return p;
    };
    unsigned short* wt1  = (unsigned short*)alloc((size_t)256 * 128 * 2);
    unsigned short* wt2  = (unsigned short*)alloc((size_t)128 * 256 * 2);
    unsigned short* h1b  = (unsigned short*)alloc((size_t)N * 256 * 2);
    unsigned short* h2b  = (unsigned short*)alloc((size_t)N * 128 * 2);
    float* as1 = (float*)alloc((size_t)N * 4 * 4);
    float* ad1 = (float*)alloc((size_t)N * 4 * 4);
    float* as2 = (float*)alloc((size_t)N * 4);
    float* ad2 = (float*)alloc((size_t)N * 4);
    int* deg  = (int*)alloc((size_t)N * 4);
    int* idx  = (int*)alloc((size_t)EA * 4);
    int* offs = (int*)alloc((size_t)(N + 1) * 4);
    int* bsum = (int*)alloc((size_t)1024 * 4);
    int* colb = (int*)alloc((size_t)EA * 4);
    uint2* p1 = (uint2*)alloc((size_t)EA * 8);

    const int nb = (N + 1 + 1023) / 1024;

    prep_kernel<<<(2 * 128 * 256 + N + 255) / 256, 256, 0, stream>>>(W1, W2, wt1, wt2, deg, N);
    degree_kernel<<<(EA + 255) / 256, 256, 0, stream>>>(ei, E, N, deg, idx);
    scan_local<<<nb, 1024, 0, stream>>>(deg, offs, bsum, N);

    gemm1_mfma<<<(N + 63) / 64, 256, 0, stream>>>(x, wt1, at_s1, at_d1, h1b, as1, ad1, N);
    scatter_kernel<<<(EA + 255) / 256, 256, 0, stream>>>(ei, E, N, offs, idx, bsum, nb,
                                                         as1, ad1, colb, p1);
    agg1_gemm2<<<(N + 15) / 16, 128, 0, stream>>>(h1b, colb, p1, offs, bsum, nb, b1,
                                                  wt2, at_s2, at_d2, h2b, as2, ad2, N);
    agg2_kernel<<<(N + 3) / 4, 256, 0, stream>>>(h2b, as2, ad2, offs, colb, bsum, nb,
                                                 b2, out, N);
}

// Round 16
// 311.305 us; speedup vs baseline: 1.0513x; 1.0513x over previous
//
#include <hip/hip_runtime.h>
#include <hip/hip_bf16.h>

#define NEG_SLOPE 0.2f

typedef short bf16x8 __attribute__((ext_vector_type(8)));
typedef float f32x4 __attribute__((ext_vector_type(4)));
typedef float f32x2 __attribute__((ext_vector_type(2)));

__device__ __forceinline__ unsigned short f2bf(float f) {
    unsigned int x = __float_as_uint(f);
    unsigned int lsb = (x >> 16) & 1u;
    x += 0x7fffu + lsb;
    return (unsigned short)(x >> 16);
}
__device__ __forceinline__ f32x2 upk(unsigned int u) {
    f32x2 r;
    r.x = __uint_as_float(u << 16);
    r.y = __uint_as_float(u & 0xffff0000u);
    return r;
}
__device__ __forceinline__ unsigned short f2h(float f) {
    _Float16 h = (_Float16)f;
    return *(unsigned short*)&h;
}
__device__ __forceinline__ float h2f(unsigned short u) {
    _Float16 h = *(_Float16*)&u;
    return (float)h;
}

// per-lane exclusive prefix of bsum[0..nb); consumers pick with __shfl.
// ALL 64 lanes of the wave must be active.
__device__ __forceinline__ int bsum_scan(const int* __restrict__ bsum, int nb) {
    int lane = threadIdx.x & 63;
    int v = (lane < nb) ? bsum[lane] : 0;
    int x = v;
    #pragma unroll
    for (int off = 1; off < 64; off <<= 1) {
        int t = __shfl_up(x, off);
        if (lane >= off) x += t;
    }
    return x - v;
}

// ---------------- prep: cast both weights + zero deg (one launch) ----------
__global__ void prep_kernel(const float* __restrict__ W1, const float* __restrict__ W2,
                            unsigned short* __restrict__ wt1, unsigned short* __restrict__ wt2,
                            int* __restrict__ deg, int N) {
    int idx = blockIdx.x * 256 + threadIdx.x;
    if (idx < 128 * 256) {
        int k = idx >> 8, n = idx & 255;
        wt1[(size_t)n * 128 + k] = f2bf(W1[idx]);
    } else if (idx < 2 * 128 * 256) {
        int j = idx - 128 * 256;
        int k = j >> 7, n = j & 127;
        wt2[(size_t)n * 256 + k] = f2bf(W2[j]);
    } else {
        int i = idx - 2 * 128 * 256;
        if (i < N) deg[i] = 0;
    }
}

// ---------------- CSR build ----------------
__global__ void degree_kernel(const int* __restrict__ ei, int E, int N,
                              int* __restrict__ deg, int* __restrict__ idx) {
    int e = blockIdx.x * blockDim.x + threadIdx.x;
    int EA = E + N;
    if (e >= EA) return;
    int dst = (e < E) ? ei[E + e] : (e - E);
    idx[e] = atomicAdd(&deg[dst], 1);
}

// per-block (1024) local exclusive scan; offs = LOCAL prefixes, bsum = totals.
__global__ void scan_local(const int* __restrict__ deg, int* __restrict__ offs,
                           int* __restrict__ bsum, int N) {
    __shared__ int wsum[16];
    int tid = threadIdx.x;
    int lane = tid & 63;
    int wave = tid >> 6;
    int i = blockIdx.x * 1024 + tid;
    int v = (i < N) ? deg[i] : 0;
    int x = v;
    #pragma unroll
    for (int off = 1; off < 64; off <<= 1) {
        int t = __shfl_up(x, off);
        if (lane >= off) x += t;
    }
    if (lane == 63) wsum[wave] = x;
    __syncthreads();
    if (wave == 0 && lane < 16) {
        int w = wsum[lane];
        #pragma unroll
        for (int off = 1; off < 16; off <<= 1) {
            int t = __shfl_up(w, off);
            if (lane >= off) w += t;
        }
        wsum[lane] = w;
    }
    __syncthreads();
    int wexcl = (wave > 0) ? wsum[wave - 1] : 0;
    if (i <= N) offs[i] = wexcl + x - v;
    if (tid == 0) bsum[blockIdx.x] = wsum[15];
}

// scatter (no atomics) + fused layer-1 edge-weight precompute (fp16 x4)
__global__ void scatter_kernel(const int* __restrict__ ei, int E, int N,
                               const int* __restrict__ offs, const int* __restrict__ idx,
                               const int* __restrict__ bsum, int nb,
                               const float* __restrict__ as1, const float* __restrict__ ad1,
                               int* __restrict__ colb, uint2* __restrict__ p1) {
    int e = blockIdx.x * blockDim.x + threadIdx.x;
    int EA = E + N;
    bool act = e < EA;
    int s = 0, d = 0;
    if (act) {
        if (e < E) { s = ei[e]; d = ei[E + e]; }
        else       { s = d = e - E; }
    }
    int pref = bsum_scan(bsum, nb);
    int excl = __shfl(pref, d >> 10);
    if (!act) return;
    int pos = offs[d] + excl + idx[e];
    colb[pos] = s << 9;
    float4 av = *(const float4*)(as1 + s * 4);
    float4 dv = *(const float4*)(ad1 + d * 4);
    float e0 = av.x + dv.x, e1 = av.y + dv.y, e2 = av.z + dv.z, e3 = av.w + dv.w;
    e0 = (e0 > 0.f) ? e0 : NEG_SLOPE * e0;
    e1 = (e1 > 0.f) ? e1 : NEG_SLOPE * e1;
    e2 = (e2 > 0.f) ? e2 : NEG_SLOPE * e2;
    e3 = (e3 > 0.f) ? e3 : NEG_SLOPE * e3;
    uint2 q;
    q.x = (unsigned int)f2h(__expf(e0)) | ((unsigned int)f2h(__expf(e1)) << 16);
    q.y = (unsigned int)f2h(__expf(e2)) | ((unsigned int)f2h(__expf(e3)) << 16);
    p1[pos] = q;
}

// ---------------- MFMA GEMM1 + fused x-cast + fused alpha1 ----------------
__global__ void gemm1_mfma(const float* __restrict__ A,
                           const unsigned short* __restrict__ Wt,
                           const float* __restrict__ att_s, const float* __restrict__ att_d,
                           unsigned short* __restrict__ hb,
                           float* __restrict__ as, float* __restrict__ ad, int M) {
    int wave = threadIdx.x >> 6;
    int lane = threadIdx.x & 63;
    int quad = lane >> 4;
    int l16 = lane & 15;
    int m0 = blockIdx.x * 64 + wave * 16;
    int rowc = min(m0 + l16, M - 1);
    bf16x8 a[4];
    const float* ap = A + (size_t)rowc * 128 + quad * 8;
    #pragma unroll
    for (int kc = 0; kc < 4; ++kc) {
        float4 f0 = *(const float4*)(ap + kc * 32);
        float4 f1 = *(const float4*)(ap + kc * 32 + 4);
        bf16x8 v;
        v[0] = (short)f2bf(f0.x); v[1] = (short)f2bf(f0.y);
        v[2] = (short)f2bf(f0.z); v[3] = (short)f2bf(f0.w);
        v[4] = (short)f2bf(f1.x); v[5] = (short)f2bf(f1.y);
        v[6] = (short)f2bf(f1.z); v[7] = (short)f2bf(f1.w);
        a[kc] = v;
    }
    f32x4 acc[16];
    #pragma unroll
    for (int nt = 0; nt < 16; ++nt) {
        f32x4 c = {0.f, 0.f, 0.f, 0.f};
        const unsigned short* bp = Wt + (size_t)(nt * 16 + l16) * 128 + quad * 8;
        #pragma unroll
        for (int kc = 0; kc < 4; ++kc) {
            bf16x8 b = *(const bf16x8*)(bp + kc * 32);
            c = __builtin_amdgcn_mfma_f32_16x16x32_bf16(a[kc], b, c, 0, 0, 0);
        }
        acc[nt] = c;
    }
    float asv[16], adv[16];
    #pragma unroll
    for (int nt = 0; nt < 16; ++nt) {
        asv[nt] = att_s[nt * 16 + l16];
        adv[nt] = att_d[nt * 16 + l16];
    }
    int srow0 = m0 + quad * 4;
    #pragma unroll
    for (int r = 0; r < 4; ++r) {
        int srow = srow0 + r;
        bool ok = srow < M;
        if (ok) {
            #pragma unroll
            for (int nt = 0; nt < 16; ++nt)
                hb[(size_t)srow * 256 + nt * 16 + l16] = f2bf(acc[nt][r]);
        }
        #pragma unroll
        for (int h = 0; h < 4; ++h) {
            float ps = acc[4 * h][r] * asv[4 * h] + acc[4 * h + 1][r] * asv[4 * h + 1]
                     + acc[4 * h + 2][r] * asv[4 * h + 2] + acc[4 * h + 3][r] * asv[4 * h + 3];
            float pd = acc[4 * h][r] * adv[4 * h] + acc[4 * h + 1][r] * adv[4 * h + 1]
                     + acc[4 * h + 2][r] * adv[4 * h + 2] + acc[4 * h + 3][r] * adv[4 * h + 3];
            #pragma unroll
            for (int off = 1; off < 16; off <<= 1) {
                ps += __shfl_xor(ps, off);
                pd += __shfl_xor(pd, off);
            }
            if (ok && l16 == 0) {
                as[srow * 4 + h] = ps;
                ad[srow * 4 + h] = pd;
            }
        }
    }
}

// ---------------- FUSED: layer-1 aggregation + GEMM2 + alpha2 ----------------
// R14 structure (256 threads, 4 waves x 4 nodes, one barrier, XOR-swizzled
// unpadded [16][256] tile, 0 conflicts) + p1 per-head ushort read.
__global__ void agg1_gemm2(const unsigned short* __restrict__ hb,
                           const int* __restrict__ colb, const uint2* __restrict__ p1,
                           const int* __restrict__ offs,
                           const int* __restrict__ bsum, int nb,
                           const float* __restrict__ b1,
                           const unsigned short* __restrict__ Wt,
                           const float* __restrict__ att_s, const float* __restrict__ att_d,
                           unsigned short* __restrict__ h2b,
                           float* __restrict__ as2, float* __restrict__ ad2, int N) {
    __shared__ unsigned short Atile[16][256];   // 8 KB, XOR-swizzled
    __shared__ float asP[16], adP[16];
    int tid = threadIdx.x;
    int wave = tid >> 6;
    int lane = tid & 63;
    if (tid < 16) { asP[tid] = 0.f; adP[tid] = 0.f; }
    int half = lane >> 5;
    int sub  = lane & 31;
    int head = sub >> 3;
    int c0b = sub * 16;
    const char* hpc = (const char*)hb;
    const unsigned short* p1u = (const unsigned short*)p1;
    int node0 = blockIdx.x * 16;
    int pref = bsum_scan(bsum, nb);

    // ---- phase 1: each wave aggregates 4 nodes into swizzled tile rows ----
    for (int t = 0; t < 4; ++t) {
        int lrow = wave * 4 + t;
        int node = min(node0 + lrow, N - 1);
        int beg = offs[node] + __shfl(pref, node >> 10);
        int end = offs[node + 1] + __shfl(pref, (node + 1) >> 10);
        float d = 0.f;
        f32x2 acc[4] = {};
        int j = beg + half;
        for (; j + 6 < end; j += 8) {
            int o0 = colb[j] + c0b;
            int o1 = colb[j + 2] + c0b;
            int o2 = colb[j + 4] + c0b;
            int o3 = colb[j + 6] + c0b;
            float p0 = h2f(p1u[(size_t)j * 4 + head]);
            float p1v = h2f(p1u[(size_t)(j + 2) * 4 + head]);
            float p2 = h2f(p1u[(size_t)(j + 4) * 4 + head]);
            float p3 = h2f(p1u[(size_t)(j + 6) * 4 + head]);
            uint4 g0 = *(const uint4*)(hpc + o0);
            uint4 g1 = *(const uint4*)(hpc + o1);
            uint4 g2 = *(const uint4*)(hpc + o2);
            uint4 g3 = *(const uint4*)(hpc + o3);
            d += (p0 + p1v) + (p2 + p3);
            const unsigned int* w0 = (const unsigned int*)&g0;
            const unsigned int* w1 = (const unsigned int*)&g1;
            const unsigned int* w2 = (const unsigned int*)&g2;
            const unsigned int* w3 = (const unsigned int*)&g3;
            f32x2 v0 = {p0, p0}, v1 = {p1v, p1v}, v2 = {p2, p2}, v3 = {p3, p3};
            #pragma unroll
            for (int i = 0; i < 4; ++i) {
                acc[i] = __builtin_elementwise_fma(v0, upk(w0[i]), acc[i]);
                acc[i] = __builtin_elementwise_fma(v1, upk(w1[i]), acc[i]);
                acc[i] = __builtin_elementwise_fma(v2, upk(w2[i]), acc[i]);
                acc[i] = __builtin_elementwise_fma(v3, upk(w3[i]), acc[i]);
            }
        }
        for (; j < end; j += 2) {
            int o = colb[j] + c0b;
            float p = h2f(p1u[(size_t)j * 4 + head]);
            uint4 g = *(const uint4*)(hpc + o);
            d += p;
            const unsigned int* w = (const unsigned int*)&g;
            f32x2 v = {p, p};
            #pragma unroll
            for (int i = 0; i < 4; ++i)
                acc[i] = __builtin_elementwise_fma(v, upk(w[i]), acc[i]);
        }
        d += __shfl_xor(d, 32);
        #pragma unroll
        for (int i = 0; i < 4; ++i) {
            acc[i].x += __shfl_xor(acc[i].x, 32);
            acc[i].y += __shfl_xor(acc[i].y, 32);
        }
        if (half == 0) {
            float inv = 1.f / d;
            int c0 = sub * 8;
            float4 bb0 = *(const float4*)(b1 + c0);
            float4 bb1 = *(const float4*)(b1 + c0 + 4);
            float av[8] = {acc[0].x, acc[0].y, acc[1].x, acc[1].y,
                           acc[2].x, acc[2].y, acc[3].x, acc[3].y};
            float bb[8] = {bb0.x, bb0.y, bb0.z, bb0.w, bb1.x, bb1.y, bb1.z, bb1.w};
            unsigned short o[8];
            #pragma unroll
            for (int i = 0; i < 8; ++i) {
                float v = av[i] * inv + bb[i];
                v = (v > 0.f) ? v : (__expf(v) - 1.f);
                o[i] = f2bf(v);
            }
            uint4 pk;
            pk.x = (unsigned int)o[0] | ((unsigned int)o[1] << 16);
            pk.y = (unsigned int)o[2] | ((unsigned int)o[3] << 16);
            pk.z = (unsigned int)o[4] | ((unsigned int)o[5] << 16);
            pk.w = (unsigned int)o[6] | ((unsigned int)o[7] << 16);
            *(uint4*)&Atile[lrow][(sub ^ lrow) * 8] = pk;   // swizzled group
        }
    }
    __syncthreads();

    // ---- phase 2: 16x128 = Atile(16x256) @ wt2; wave owns n-tiles 2w,2w+1 ----
    int quad = lane >> 4;
    int l16 = lane & 15;
    bf16x8 a[8];
    #pragma unroll
    for (int kc = 0; kc < 8; ++kc) {
        int grp = (kc * 4 + quad) ^ l16;             // unswizzle for row l16
        a[kc] = *(const bf16x8*)&Atile[l16][grp * 8];
    }
    int nt0 = wave * 2;
    f32x4 acc2[2];
    #pragma unroll
    for (int i = 0; i < 2; ++i) {
        f32x4 c = {0.f, 0.f, 0.f, 0.f};
        const unsigned short* bp = Wt + (size_t)((nt0 + i) * 16 + l16) * 256 + quad * 8;
        #pragma unroll
        for (int kc = 0; kc < 8; ++kc) {
            bf16x8 b = *(const bf16x8*)(bp + kc * 32);
            c = __builtin_amdgcn_mfma_f32_16x16x32_bf16(a[kc], b, c, 0, 0, 0);
        }
        acc2[i] = c;
    }
    float s0 = att_s[nt0 * 16 + l16], s1 = att_s[(nt0 + 1) * 16 + l16];
    float d0 = att_d[nt0 * 16 + l16], d1 = att_d[(nt0 + 1) * 16 + l16];
    #pragma unroll
    for (int r = 0; r < 4; ++r) {
        int row = quad * 4 + r;
        int grow = node0 + row;
        if (grow < N) {
            h2b[(size_t)grow * 128 + nt0 * 16 + l16] = f2bf(acc2[0][r]);
            h2b[(size_t)grow * 128 + (nt0 + 1) * 16 + l16] = f2bf(acc2[1][r]);
        }
        float ps = acc2[0][r] * s0 + acc2[1][r] * s1;
        float pd = acc2[0][r] * d0 + acc2[1][r] * d1;
        #pragma unroll
        for (int off = 1; off < 16; off <<= 1) {
            ps += __shfl_xor(ps, off);
            pd += __shfl_xor(pd, off);
        }
        if (l16 == 0) {
            atomicAdd(&asP[row], ps);
            atomicAdd(&adP[row], pd);
        }
    }
    __syncthreads();
    if (tid < 16 && node0 + tid < N) {
        as2[node0 + tid] = asP[tid];
        ad2[node0 + tid] = adP[tid];
    }
}

// ---------------- layer-2 aggregation (hoisted bsum scan) ----------------
__global__ void agg2_kernel(const unsigned short* __restrict__ hb,
                            const float* __restrict__ as,
                            const float* __restrict__ ad,
                            const int* __restrict__ offs, const int* __restrict__ colb,
                            const int* __restrict__ bsum, int nb,
                            const float* __restrict__ b2,
                            float* __restrict__ out, int N) {
    int node = blockIdx.x * 4 + (threadIdx.x >> 6);
    if (node >= N) return;
    int lane = threadIdx.x & 63;
    int q   = lane >> 4;
    int sub = lane & 15;
    int c0b = sub * 16;
    const char* hpc = (const char*)hb;
    float adv = ad[node];
    int pref = bsum_scan(bsum, nb);
    int beg = offs[node] + __shfl(pref, node >> 10);
    int end = offs[node + 1] + __shfl(pref, (node + 1) >> 10);
    float d = 0.f;
    f32x2 acc[4] = {};
    int j = beg + q;
    for (; j + 4 < end; j += 8) {
        int cb0 = colb[j];
        int cb1 = colb[j + 4];
        uint4 g0 = *(const uint4*)(hpc + (cb0 >> 1) + c0b);
        uint4 g1 = *(const uint4*)(hpc + (cb1 >> 1) + c0b);
        float e0 = as[cb0 >> 9] + adv;
        float e1 = as[cb1 >> 9] + adv;
        e0 = (e0 > 0.f) ? e0 : NEG_SLOPE * e0;
        e1 = (e1 > 0.f) ? e1 : NEG_SLOPE * e1;
        float p0 = __expf(e0), p1 = __expf(e1);
        d += p0 + p1;
        const unsigned int* w0 = (const unsigned int*)&g0;
        const unsigned int* w1 = (const unsigned int*)&g1;
        f32x2 v0 = {p0, p0}, v1 = {p1, p1};
        #pragma unroll
        for (int i = 0; i < 4; ++i) {
            acc[i] = __builtin_elementwise_fma(v0, upk(w0[i]), acc[i]);
            acc[i] = __builtin_elementwise_fma(v1, upk(w1[i]), acc[i]);
        }
    }
    for (; j < end; j += 4) {
        int cb = colb[j];
        uint4 g = *(const uint4*)(hpc + (cb >> 1) + c0b);
        float e = as[cb >> 9] + adv;
        e = (e > 0.f) ? e : NEG_SLOPE * e;
        float p = __expf(e);
        d += p;
        const unsigned int* w = (const unsigned int*)&g;
        f32x2 v = {p, p};
        #pragma unroll
        for (int i = 0; i < 4; ++i)
            acc[i] = __builtin_elementwise_fma(v, upk(w[i]), acc[i]);
    }
    d += __shfl_xor(d, 16);
    d += __shfl_xor(d, 32);
    #pragma unroll
    for (int i = 0; i < 4; ++i) {
        acc[i].x += __shfl_xor(acc[i].x, 16);
        acc[i].x += __shfl_xor(acc[i].x, 32);
        acc[i].y += __shfl_xor(acc[i].y, 16);
        acc[i].y += __shfl_xor(acc[i].y, 32);
    }
    if (lane < 16) {
        float inv = 1.f / d;
        int c0 = sub * 8;
        float4 bb0 = *(const float4*)(b2 + c0);
        float4 bb1 = *(const float4*)(b2 + c0 + 4);
        float av[8] = {acc[0].x, acc[0].y, acc[1].x, acc[1].y,
                       acc[2].x, acc[2].y, acc[3].x, acc[3].y};
        float bb[8] = {bb0.x, bb0.y, bb0.z, bb0.w, bb1.x, bb1.y, bb1.z, bb1.w};
        *(float4*)(out + (size_t)node * 128 + c0) =
            make_float4(av[0] * inv + bb[0], av[1] * inv + bb[1],
                        av[2] * inv + bb[2], av[3] * inv + bb[3]);
        *(float4*)(out + (size_t)node * 128 + c0 + 4) =
            make_float4(av[4] * inv + bb[4], av[5] * inv + bb[5],
                        av[6] * inv + bb[6], av[7] * inv + bb[7]);
    }
}

// ---------------- launch (7 dispatches) ----------------

extern "C" void kernel_launch(void* const* d_in, const int* in_sizes, int n_in,
                              void* d_out, int out_size, void* d_ws, size_t ws_size,
                              hipStream_t stream) {
    const float* x    = (const float*)d_in[0];
    const int*   ei   = (const int*)d_in[1];
    const float* W1   = (const float*)d_in[2];
    const float* at_s1 = (const float*)d_in[3];
    const float* at_d1 = (const float*)d_in[4];
    const float* b1   = (const float*)d_in[5];
    const float* W2   = (const float*)d_in[6];
    const float* at_s2 = (const float*)d_in[7];
    const float* at_d2 = (const float*)d_in[8];
    const float* b2   = (const float*)d_in[9];
    float* out = (float*)d_out;

    const int N  = in_sizes[0] / 128;
    const int E  = in_sizes[1] / 2;
    const int EA = E + N;

    char* ws = (char*)d_ws;
    size_t off = 0;
    auto alloc = [&](size_t bytes) -> void* {
        void* p = ws + off;
        off += (bytes + 255) & ~(size_t)255;
        return p;
    };
    unsigned short* wt1  = (unsigned short*)alloc((size_t)256 * 128 * 2);
    unsigned short* wt2  = (unsigned short*)alloc((size_t)128 * 256 * 2);
    unsigned short* h1b  = (unsigned short*)alloc((size_t)N * 256 * 2);
    unsigned short* h2b  = (unsigned short*)alloc((size_t)N * 128 * 2);
    float* as1 = (float*)alloc((size_t)N * 4 * 4);
    float* ad1 = (float*)alloc((size_t)N * 4 * 4);
    float* as2 = (float*)alloc((size_t)N * 4);
    float* ad2 = (float*)alloc((size_t)N * 4);
    int* deg  = (int*)alloc((size_t)N * 4);
    int* idx  = (int*)alloc((size_t)EA * 4);
    int* offs = (int*)alloc((size_t)(N + 1) * 4);
    int* bsum = (int*)alloc((size_t)1024 * 4);
    int* colb = (int*)alloc((size_t)EA * 4);
    uint2* p1 = (uint2*)alloc((size_t)EA * 8);

    const int nb = (N + 1 + 1023) / 1024;

    prep_kernel<<<(2 * 128 * 256 + N + 255) / 256, 256, 0, stream>>>(W1, W2, wt1, wt2, deg, N);
    degree_kernel<<<(EA + 255) / 256, 256, 0, stream>>>(ei, E, N, deg, idx);
    scan_local<<<nb, 1024, 0, stream>>>(deg, offs, bsum, N);

    gemm1_mfma<<<(N + 63) / 64, 256, 0, stream>>>(x, wt1, at_s1, at_d1, h1b, as1, ad1, N);
    scatter_kernel<<<(EA + 255) / 256, 256, 0, stream>>>(ei, E, N, offs, idx, bsum, nb,
                                                         as1, ad1, colb, p1);
    agg1_gemm2<<<(N + 15) / 16, 256, 0, stream>>>(h1b, colb, p1, offs, bsum, nb, b1,
                                                  wt2, at_s2, at_d2, h2b, as2, ad2, N);
    agg2_kernel<<<(N + 3) / 4, 256, 0, stream>>>(h2b, as2, ad2, offs, colb, bsum, nb,
                                                 b2, out, N);
}